// Round 1
// baseline (485.210 us; speedup 1.0000x reference)
//
#include <hip/hip_runtime.h>
#include <hip/hip_bf16.h>

// CreateProposal (Faster-RCNN proposal layer), H=W=100, 9 anchors, stride 16.
// Pipeline:
//   k_hist      (1 block)  : score-bit histogram -> bit threshold for ~top-6000;
//                            zero keys/counter and the 300x5 output head.
//   k_anchors   (grid)     : write all 90000 anchors to d_out+1500 (exact ints).
//   k_compact   (grid)     : compact candidate keys (score_bits<<32 | ~idx).
//   k_sortboxes (1 block)  : bitonic sort 8192 keys desc in LDS; decode+clip
//                            the top-6000 proposals -> ws.
//   k_nms       (1 block)  : chunked greedy NMS (exact sequential semantics),
//                            early-exit at 300 keeps; write output rows.

#define W100 100
#define HW10K 10000
#define NANCH 90000
#define PRE_TOPN 6000
#define POST_TOPN 300
#define PADN 8192          // padded sort size (pow2 >= worst-case compact count)
#define NMS_TH 0.7f

typedef unsigned long long u64;
typedef unsigned u32;

__constant__ float c_anch[9][4] = {
    {-84.f,  -40.f,  99.f,  55.f},
    {-176.f, -88.f,  191.f, 103.f},
    {-360.f, -184.f, 375.f, 199.f},
    {-56.f,  -56.f,  71.f,  71.f},
    {-120.f, -120.f, 135.f, 135.f},
    {-248.f, -248.f, 263.f, 263.f},
    {-36.f,  -80.f,  51.f,  95.f},
    {-80.f,  -168.f, 95.f,  183.f},
    {-168.f, -344.f, 183.f, 359.f}
};

// ---------------- histogram + threshold (single block, 1024 thr) -------------
__global__ __launch_bounds__(1024)
void k_hist(const float* __restrict__ scores, u64* __restrict__ keys,
            u32* __restrict__ meta, float* __restrict__ out) {
    __shared__ u32 hist[8192];     // buckets of score_bits >> 17
    __shared__ u32 gsum[1024];
    const int tid = threadIdx.x;

    for (int i = tid; i < 8192; i += 1024) hist[i] = 0u;
    __syncthreads();

    const float* fg = scores + 9 * HW10K;   // fg channels, 90000 contiguous floats
    for (int i = tid; i < NANCH; i += 1024) {
        u32 b = __float_as_uint(fg[i]);     // scores in [0,1): positive, monotone bits
        atomicAdd(&hist[b >> 17], 1u);
    }
    __syncthreads();

    // per-thread partial (8 buckets each), then Hillis-Steele suffix scan
    u32 gs = 0;
#pragma unroll
    for (int b = 0; b < 8; ++b) gs += hist[tid * 8 + b];
    gsum[tid] = gs;
    __syncthreads();
    for (int d = 1; d < 1024; d <<= 1) {
        u32 add = (tid + d < 1024) ? gsum[tid + d] : 0u;
        __syncthreads();
        gsum[tid] += add;
        __syncthreads();
    }
    // crossing group: gsuf[g] >= 6000 > gsuf[g+1]
    u32 nxt = (tid < 1023) ? gsum[tid + 1] : 0u;
    if (gsum[tid] >= (u32)PRE_TOPN && nxt < (u32)PRE_TOPN) {
        u32 run = nxt;
        u32 T = (u32)tid * 8u;
        for (int b = 7; b >= 0; --b) {
            run += hist[tid * 8 + b];
            if (run >= (u32)PRE_TOPN) { T = (u32)tid * 8u + (u32)b; break; }
        }
        meta[1] = T << 17;   // admit all score_bits >= meta[1]
        meta[0] = 0u;        // compact counter
    }

    // zero the padded key buffer and the 300x5 output head (poisoned scratch)
    for (int i = tid; i < PADN; i += 1024) keys[i] = 0ull;
    for (int i = tid; i < POST_TOPN * 5; i += 1024) out[i] = 0.f;
}

// ---------------- anchors output (exact) -------------------------------------
__global__ void k_anchors(float4* __restrict__ anc_out) {
    int idx = blockIdx.x * blockDim.x + threadIdx.x;
    if (idx >= NANCH) return;
    int a = idx % 9, pos = idx / 9;
    int y = pos / W100, x = pos - y * W100;
    float sx = (float)(x * 16), sy = (float)(y * 16);
    anc_out[idx] = make_float4(c_anch[a][0] + sx, c_anch[a][1] + sy,
                               c_anch[a][2] + sx, c_anch[a][3] + sy);
}

// ---------------- compact candidates -----------------------------------------
__global__ void k_compact(const float* __restrict__ scores, u32* __restrict__ meta,
                          u64* __restrict__ keys) {
    int idx = blockIdx.x * blockDim.x + threadIdx.x;
    if (idx >= NANCH) return;
    int pos = idx / 9;
    int a = idx - pos * 9;
    u32 bits = __float_as_uint(scores[(9 + a) * HW10K + pos]);
    if (bits >= meta[1]) {
        u32 slot = atomicAdd(&meta[0], 1u);
        if (slot < (u32)PADN)
            keys[slot] = ((u64)bits << 32) | (u32)(~(u32)idx);
    }
}

// ---------------- sort (bitonic, desc) + decode top-6000 boxes ---------------
__global__ __launch_bounds__(1024)
void k_sortboxes(const u64* __restrict__ keysg, const float* __restrict__ bbox,
                 const float* __restrict__ im_info, float4* __restrict__ boxes) {
    __shared__ u64 s[PADN];   // 64 KiB
    const int tid = threadIdx.x;
    for (int i = tid; i < PADN; i += 1024) s[i] = keysg[i];
    __syncthreads();

    for (u32 k = 2; k <= (u32)PADN; k <<= 1) {
        for (u32 j = k >> 1; j > 0; j >>= 1) {
            for (u32 p = tid; p < (u32)PADN / 2; p += 1024) {
                u32 i  = 2u * p - (p & (j - 1u));
                u32 ix = i | j;
                u64 A = s[i], B = s[ix];
                bool asc = (i & k) != 0u;          // overall DESCENDING sort
                bool sw  = asc ? (A > B) : (A < B);
                if (sw) { s[i] = B; s[ix] = A; }
            }
            __syncthreads();
        }
    }

    const float imH = im_info[0], imW = im_info[1];
    for (int p = tid; p < PRE_TOPN; p += 1024) {
        u32 idx = ~((u32)s[p]);
        int pos = (int)(idx / 9u);
        int a   = (int)(idx - (u32)pos * 9u);
        int y = pos / W100, x = pos - y * W100;
        float sx = (float)(x * 16), sy = (float)(y * 16);
        float ax1 = c_anch[a][0] + sx, ay1 = c_anch[a][1] + sy;
        float ax2 = c_anch[a][2] + sx, ay2 = c_anch[a][3] + sy;
        float w = ax2 - ax1 + 1.f, h = ay2 - ay1 + 1.f;
        float cx = ax1 + 0.5f * w,  cy = ay1 + 0.5f * h;
        float dx = bbox[(a * 4 + 0) * HW10K + pos];
        float dy = bbox[(a * 4 + 1) * HW10K + pos];
        float dw = bbox[(a * 4 + 2) * HW10K + pos];
        float dh = bbox[(a * 4 + 3) * HW10K + pos];
        float pcx = dx * w + cx, pcy = dy * h + cy;
        float pw = expf(dw) * w, ph = expf(dh) * h;
        float x1 = pcx - 0.5f * pw, y1 = pcy - 0.5f * ph;
        float x2 = pcx + 0.5f * pw, y2 = pcy + 0.5f * ph;
        x1 = fminf(fmaxf(x1, 0.f), imW - 1.f);
        x2 = fminf(fmaxf(x2, 0.f), imW - 1.f);
        y1 = fminf(fmaxf(y1, 0.f), imH - 1.f);
        y2 = fminf(fmaxf(y2, 0.f), imH - 1.f);
        boxes[p] = make_float4(x1, y1, x2, y2);
    }
}

// ---------------- greedy NMS (exact), chunked, early-exit --------------------
__global__ __launch_bounds__(1024)
void k_nms(const float4* __restrict__ bx, float* __restrict__ out) {
    __shared__ unsigned char supp[PRE_TOPN];
    __shared__ float4 ck[64];
    __shared__ int s_rank, s_nk;
    const int tid = threadIdx.x;

    for (int i = tid; i < PRE_TOPN; i += 1024) supp[i] = 0;
    if (tid == 0) s_rank = 0;
    __syncthreads();

    for (int c = 0; c < (PRE_TOPN + 63) / 64; ++c) {
        const int base = c * 64;
        if (tid < 64) {                        // wave 0: sequential greedy inside chunk
            int j = base + tid;
            bool valid = j < PRE_TOPN;
            float4 b = valid ? bx[j] : make_float4(0.f, 0.f, 0.f, 0.f);
            bool dead = !valid || (supp[j] != 0);
            float area = (b.z - b.x + 1.f) * (b.w - b.y + 1.f);
            for (int k = 0; k < 64; ++k) {
                int   dk = __shfl(dead ? 1 : 0, k);
                float kx1 = __shfl(b.x, k), ky1 = __shfl(b.y, k);
                float kx2 = __shfl(b.z, k), ky2 = __shfl(b.w, k);
                float ka  = __shfl(area, k);
                if (!dk && tid > k && !dead) {
                    float iw = fmaxf(fminf(b.z, kx2) - fmaxf(b.x, kx1) + 1.f, 0.f);
                    float ih = fmaxf(fminf(b.w, ky2) - fmaxf(b.y, ky1) + 1.f, 0.f);
                    float inter = iw * ih;
                    float iou = inter / ((area + ka) - inter);
                    if (iou > NMS_TH) dead = true;
                }
            }
            u64 kept = __ballot(!dead && valid);
            int rin = __popcll(kept & ((1ull << tid) - 1ull));
            int r0 = s_rank;                   // read before lane-0 update (in-order wave)
            if (!dead && valid) {
                ck[rin] = b;
                int r = r0 + rin;
                if (r < POST_TOPN) {
                    out[r * 5 + 0] = 0.f;
                    out[r * 5 + 1] = b.x; out[r * 5 + 2] = b.y;
                    out[r * 5 + 3] = b.z; out[r * 5 + 4] = b.w;
                }
            } else if (valid) {
                supp[j] = 1;
            }
            if (tid == 0) { s_nk = __popcll(kept); s_rank = r0 + s_nk; }
        }
        __syncthreads();
        if (s_rank >= POST_TOPN) break;        // uniform: no further ranks < 300 possible
        const int nk = s_nk;
        if (nk > 0) {                          // all threads: suppress the tail
            for (int j = base + 64 + tid; j < PRE_TOPN; j += 1024) {
                if (supp[j]) continue;
                float4 b = bx[j];
                float area = (b.z - b.x + 1.f) * (b.w - b.y + 1.f);
                for (int k = 0; k < nk; ++k) {
                    float4 q = ck[k];
                    float qa = (q.z - q.x + 1.f) * (q.w - q.y + 1.f);
                    float iw = fmaxf(fminf(b.z, q.z) - fmaxf(b.x, q.x) + 1.f, 0.f);
                    float ih = fmaxf(fminf(b.w, q.w) - fmaxf(b.y, q.y) + 1.f, 0.f);
                    float inter = iw * ih;
                    float iou = inter / ((area + qa) - inter);
                    if (iou > NMS_TH) { supp[j] = 1; break; }
                }
            }
        }
        __syncthreads();
    }
}

// ---------------- launch ------------------------------------------------------
extern "C" void kernel_launch(void* const* d_in, const int* in_sizes, int n_in,
                              void* d_out, int out_size, void* d_ws, size_t ws_size,
                              hipStream_t stream) {
    const float* scores  = (const float*)d_in[0];   // (1,18,100,100)
    const float* bbox    = (const float*)d_in[1];   // (1,36,100,100)
    const float* im_info = (const float*)d_in[2];   // (3,)
    float* out = (float*)d_out;                     // 300*5 rows then 90000*4 anchors

    // workspace layout
    u64*    keys  = (u64*)d_ws;                                   // 65536 B
    float4* boxes = (float4*)((char*)d_ws + PADN * sizeof(u64));  // 96000 B
    u32*    meta  = (u32*)((char*)d_ws + PADN * sizeof(u64) + PRE_TOPN * 16); // [0]=counter [1]=thresh

    k_hist<<<1, 1024, 0, stream>>>(scores, keys, meta, out);
    k_anchors<<<(NANCH + 255) / 256, 256, 0, stream>>>((float4*)(out + POST_TOPN * 5));
    k_compact<<<(NANCH + 255) / 256, 256, 0, stream>>>(scores, meta, keys);
    k_sortboxes<<<1, 1024, 0, stream>>>(keys, bbox, im_info, boxes);
    k_nms<<<1, 1024, 0, stream>>>(boxes, out);
}

// Round 2
// 247.362 us; speedup vs baseline: 1.9615x; 1.9615x over previous
//
#include <hip/hip_runtime.h>
#include <hip/hip_bf16.h>

// CreateProposal (Faster-RCNN proposal layer), H=W=100, 9 anchors, stride 16.
// Pipeline:
//   k_hist      (1 block)  : score-bit histogram -> bit threshold for ~top-6000
//   k_anchors   (grid)     : write all 90000 anchors (exact ints)
//   k_compact   (grid)     : compact candidate keys (score_bits<<32 | ~idx)
//   k_sortboxes (1 block)  : bitonic sort 8192 keys desc; decode+clip top-6000
//   k_iou       (grid)     : pairwise suppression bitmap M[6000][94] (j>i)
//   k_scan      (1 block)  : sequential greedy scan over bitmap, early-exit 300
// Fallback k_nms (old chunked version) if ws_size too small for M.

#define W100 100
#define HW10K 10000
#define NANCH 90000
#define PRE_TOPN 6000
#define POST_TOPN 300
#define PADN 8192
#define NWORD 94           // ceil(6000/64)
#define NMS_TH 0.7f

typedef unsigned long long u64;
typedef unsigned u32;

__constant__ float c_anch[9][4] = {
    {-84.f,  -40.f,  99.f,  55.f},
    {-176.f, -88.f,  191.f, 103.f},
    {-360.f, -184.f, 375.f, 199.f},
    {-56.f,  -56.f,  71.f,  71.f},
    {-120.f, -120.f, 135.f, 135.f},
    {-248.f, -248.f, 263.f, 263.f},
    {-36.f,  -80.f,  51.f,  95.f},
    {-80.f,  -168.f, 95.f,  183.f},
    {-168.f, -344.f, 183.f, 359.f}
};

// ---------------- histogram + threshold (single block, 1024 thr) -------------
__global__ __launch_bounds__(1024)
void k_hist(const float* __restrict__ scores, u64* __restrict__ keys,
            u32* __restrict__ meta, float* __restrict__ out) {
    __shared__ u32 hist[8192];
    __shared__ u32 gsum[1024];
    const int tid = threadIdx.x;

    for (int i = tid; i < 8192; i += 1024) hist[i] = 0u;
    __syncthreads();

    const float* fg = scores + 9 * HW10K;
    for (int i = tid; i < NANCH; i += 1024) {
        u32 b = __float_as_uint(fg[i]);
        atomicAdd(&hist[b >> 17], 1u);
    }
    __syncthreads();

    u32 gs = 0;
#pragma unroll
    for (int b = 0; b < 8; ++b) gs += hist[tid * 8 + b];
    gsum[tid] = gs;
    __syncthreads();
    for (int d = 1; d < 1024; d <<= 1) {
        u32 add = (tid + d < 1024) ? gsum[tid + d] : 0u;
        __syncthreads();
        gsum[tid] += add;
        __syncthreads();
    }
    u32 nxt = (tid < 1023) ? gsum[tid + 1] : 0u;
    if (gsum[tid] >= (u32)PRE_TOPN && nxt < (u32)PRE_TOPN) {
        u32 run = nxt;
        u32 T = (u32)tid * 8u;
        for (int b = 7; b >= 0; --b) {
            run += hist[tid * 8 + b];
            if (run >= (u32)PRE_TOPN) { T = (u32)tid * 8u + (u32)b; break; }
        }
        meta[1] = T << 17;
        meta[0] = 0u;
    }

    for (int i = tid; i < PADN; i += 1024) keys[i] = 0ull;
    for (int i = tid; i < POST_TOPN * 5; i += 1024) out[i] = 0.f;
}

// ---------------- anchors output (exact) -------------------------------------
__global__ void k_anchors(float4* __restrict__ anc_out) {
    int idx = blockIdx.x * blockDim.x + threadIdx.x;
    if (idx >= NANCH) return;
    int a = idx % 9, pos = idx / 9;
    int y = pos / W100, x = pos - y * W100;
    float sx = (float)(x * 16), sy = (float)(y * 16);
    anc_out[idx] = make_float4(c_anch[a][0] + sx, c_anch[a][1] + sy,
                               c_anch[a][2] + sx, c_anch[a][3] + sy);
}

// ---------------- compact candidates -----------------------------------------
__global__ void k_compact(const float* __restrict__ scores, u32* __restrict__ meta,
                          u64* __restrict__ keys) {
    int idx = blockIdx.x * blockDim.x + threadIdx.x;
    if (idx >= NANCH) return;
    int pos = idx / 9;
    int a = idx - pos * 9;
    u32 bits = __float_as_uint(scores[(9 + a) * HW10K + pos]);
    if (bits >= meta[1]) {
        u32 slot = atomicAdd(&meta[0], 1u);
        if (slot < (u32)PADN)
            keys[slot] = ((u64)bits << 32) | (u32)(~(u32)idx);
    }
}

// ---------------- sort (bitonic, desc) + decode top-6000 boxes ---------------
__global__ __launch_bounds__(1024)
void k_sortboxes(const u64* __restrict__ keysg, const float* __restrict__ bbox,
                 const float* __restrict__ im_info, float4* __restrict__ boxes) {
    __shared__ u64 s[PADN];
    const int tid = threadIdx.x;
    for (int i = tid; i < PADN; i += 1024) s[i] = keysg[i];
    __syncthreads();

    for (u32 k = 2; k <= (u32)PADN; k <<= 1) {
        for (u32 j = k >> 1; j > 0; j >>= 1) {
            for (u32 p = tid; p < (u32)PADN / 2; p += 1024) {
                u32 i  = 2u * p - (p & (j - 1u));
                u32 ix = i | j;
                u64 A = s[i], B = s[ix];
                bool asc = (i & k) != 0u;
                bool sw  = asc ? (A > B) : (A < B);
                if (sw) { s[i] = B; s[ix] = A; }
            }
            __syncthreads();
        }
    }

    const float imH = im_info[0], imW = im_info[1];
    for (int p = tid; p < PRE_TOPN; p += 1024) {
        u32 idx = ~((u32)s[p]);
        int pos = (int)(idx / 9u);
        int a   = (int)(idx - (u32)pos * 9u);
        int y = pos / W100, x = pos - y * W100;
        float sx = (float)(x * 16), sy = (float)(y * 16);
        float ax1 = c_anch[a][0] + sx, ay1 = c_anch[a][1] + sy;
        float ax2 = c_anch[a][2] + sx, ay2 = c_anch[a][3] + sy;
        float w = ax2 - ax1 + 1.f, h = ay2 - ay1 + 1.f;
        float cx = ax1 + 0.5f * w,  cy = ay1 + 0.5f * h;
        float dx = bbox[(a * 4 + 0) * HW10K + pos];
        float dy = bbox[(a * 4 + 1) * HW10K + pos];
        float dw = bbox[(a * 4 + 2) * HW10K + pos];
        float dh = bbox[(a * 4 + 3) * HW10K + pos];
        float pcx = dx * w + cx, pcy = dy * h + cy;
        float pw = expf(dw) * w, ph = expf(dh) * h;
        float x1 = pcx - 0.5f * pw, y1 = pcy - 0.5f * ph;
        float x2 = pcx + 0.5f * pw, y2 = pcy + 0.5f * ph;
        x1 = fminf(fmaxf(x1, 0.f), imW - 1.f);
        x2 = fminf(fmaxf(x2, 0.f), imW - 1.f);
        y1 = fminf(fmaxf(y1, 0.f), imH - 1.f);
        y2 = fminf(fmaxf(y2, 0.f), imH - 1.f);
        boxes[p] = make_float4(x1, y1, x2, y2);
    }
}

// ---------------- pairwise suppression bitmap (grid) -------------------------
// M[i][w] bit k = ( IoU(box i, box 64w+k) > TH ) && (64w+k > i), upper tri only.
__global__ __launch_bounds__(64)
void k_iou(const float4* __restrict__ bx, u64* __restrict__ M) {
    const int rb = blockIdx.y, cb = blockIdx.x;
    if (cb < rb) return;
    __shared__ float4 cbox[64];
    const int tid = threadIdx.x;
    const int col0 = cb * 64;
    {
        int cj = col0 + tid;
        cbox[tid] = (cj < PRE_TOPN) ? bx[cj] : make_float4(0.f, 0.f, -2.f, -2.f);
    }
    __syncthreads();
    const int ri = rb * 64 + tid;
    if (ri >= PRE_TOPN) return;
    float4 b = bx[ri];
    float area = (b.z - b.x + 1.f) * (b.w - b.y + 1.f);
    u64 bits = 0ull;
    const int ncol = (col0 + 64 <= PRE_TOPN) ? 64 : (PRE_TOPN - col0);
#pragma unroll 8
    for (int k = 0; k < 64; ++k) {
        if (k >= ncol) break;
        float4 q = cbox[k];
        float qa = (q.z - q.x + 1.f) * (q.w - q.y + 1.f);
        float iw = fmaxf(fminf(b.z, q.z) - fmaxf(b.x, q.x) + 1.f, 0.f);
        float ih = fmaxf(fminf(b.w, q.w) - fmaxf(b.y, q.y) + 1.f, 0.f);
        float inter = iw * ih;
        float iou = inter / ((area + qa) - inter);
        if ((col0 + k > ri) && (iou > NMS_TH)) bits |= (1ull << k);
    }
    M[(size_t)ri * NWORD + cb] = bits;
}

// ---------------- sequential greedy scan over bitmap (1 block, 128 thr) ------
__global__ __launch_bounds__(128)
void k_scan(const u64* __restrict__ M, const float4* __restrict__ bx,
            float* __restrict__ out) {
    __shared__ u64 supp[NWORD];
    __shared__ u64 s_kept;
    __shared__ int s_rank;
    const int tid = threadIdx.x;
    if (tid < NWORD) supp[tid] = 0ull;
    if (tid == 0) s_rank = 0;
    __syncthreads();

    for (int c = 0; c < NWORD; ++c) {
        const int base = c * 64;
        if (tid < 64) {
            const int j = base + tid;
            const bool valid = j < PRE_TOPN;
            u64 m = valid ? M[(size_t)j * NWORD + c] : 0ull;
            float4 b = valid ? bx[j] : make_float4(0.f, 0.f, 0.f, 0.f);
            u64 alive = __ballot(valid) & ~supp[c];
            u64 kept = 0ull;
            while (alive) {
                int k = (int)__builtin_ctzll(alive);
                kept |= (1ull << k);
                u32 mlo = (u32)__builtin_amdgcn_readlane((int)(u32)m, k);
                u32 mhi = (u32)__builtin_amdgcn_readlane((int)(u32)(m >> 32), k);
                u64 mk = ((u64)mhi << 32) | mlo;
                alive &= ~mk;
                alive &= ~(1ull << k);
            }
            int r0 = s_rank;                 // read before lane-0 update (in-order wave)
            if (valid && ((kept >> tid) & 1ull)) {
                int r = r0 + (int)__popcll(kept & ((1ull << tid) - 1ull));
                if (r < POST_TOPN) {
                    out[r * 5 + 0] = 0.f;
                    out[r * 5 + 1] = b.x; out[r * 5 + 2] = b.y;
                    out[r * 5 + 3] = b.z; out[r * 5 + 4] = b.w;
                }
            }
            if (tid == 0) { s_kept = kept; s_rank = r0 + (int)__popcll(kept); }
        }
        __syncthreads();
        if (s_rank >= POST_TOPN) break;      // uniform
        const u64 kept = s_kept;
        if (kept) {
            for (int w = c + 1 + tid; w < NWORD; w += 128) {
                u64 acc = supp[w];
                u64 t = kept;
                while (t) {
                    int k = (int)__builtin_ctzll(t);
                    t &= t - 1ull;
                    acc |= M[(size_t)(base + k) * NWORD + w];
                }
                supp[w] = acc;
            }
        }
        __syncthreads();
    }
}

// ---------------- fallback chunked NMS (used only if ws too small) -----------
__global__ __launch_bounds__(1024)
void k_nms(const float4* __restrict__ bx, float* __restrict__ out) {
    __shared__ unsigned char supp[PRE_TOPN];
    __shared__ float4 ck[64];
    __shared__ int s_rank, s_nk;
    const int tid = threadIdx.x;

    for (int i = tid; i < PRE_TOPN; i += 1024) supp[i] = 0;
    if (tid == 0) s_rank = 0;
    __syncthreads();

    for (int c = 0; c < (PRE_TOPN + 63) / 64; ++c) {
        const int base = c * 64;
        if (tid < 64) {
            int j = base + tid;
            bool valid = j < PRE_TOPN;
            float4 b = valid ? bx[j] : make_float4(0.f, 0.f, 0.f, 0.f);
            bool dead = !valid || (supp[j] != 0);
            float area = (b.z - b.x + 1.f) * (b.w - b.y + 1.f);
            for (int k = 0; k < 64; ++k) {
                int   dk = __shfl(dead ? 1 : 0, k);
                float kx1 = __shfl(b.x, k), ky1 = __shfl(b.y, k);
                float kx2 = __shfl(b.z, k), ky2 = __shfl(b.w, k);
                float ka  = __shfl(area, k);
                if (!dk && tid > k && !dead) {
                    float iw = fmaxf(fminf(b.z, kx2) - fmaxf(b.x, kx1) + 1.f, 0.f);
                    float ih = fmaxf(fminf(b.w, ky2) - fmaxf(b.y, ky1) + 1.f, 0.f);
                    float inter = iw * ih;
                    float iou = inter / ((area + ka) - inter);
                    if (iou > NMS_TH) dead = true;
                }
            }
            u64 kept = __ballot(!dead && valid);
            int rin = __popcll(kept & ((1ull << tid) - 1ull));
            int r0 = s_rank;
            if (!dead && valid) {
                ck[rin] = b;
                int r = r0 + rin;
                if (r < POST_TOPN) {
                    out[r * 5 + 0] = 0.f;
                    out[r * 5 + 1] = b.x; out[r * 5 + 2] = b.y;
                    out[r * 5 + 3] = b.z; out[r * 5 + 4] = b.w;
                }
            } else if (valid) {
                supp[j] = 1;
            }
            if (tid == 0) { s_nk = __popcll(kept); s_rank = r0 + s_nk; }
        }
        __syncthreads();
        if (s_rank >= POST_TOPN) break;
        const int nk = s_nk;
        if (nk > 0) {
            for (int j = base + 64 + tid; j < PRE_TOPN; j += 1024) {
                if (supp[j]) continue;
                float4 b = bx[j];
                float area = (b.z - b.x + 1.f) * (b.w - b.y + 1.f);
                for (int k = 0; k < nk; ++k) {
                    float4 q = ck[k];
                    float qa = (q.z - q.x + 1.f) * (q.w - q.y + 1.f);
                    float iw = fmaxf(fminf(b.z, q.z) - fmaxf(b.x, q.x) + 1.f, 0.f);
                    float ih = fmaxf(fminf(b.w, q.w) - fmaxf(b.y, q.y) + 1.f, 0.f);
                    float inter = iw * ih;
                    float iou = inter / ((area + qa) - inter);
                    if (iou > NMS_TH) { supp[j] = 1; break; }
                }
            }
        }
        __syncthreads();
    }
}

// ---------------- launch ------------------------------------------------------
extern "C" void kernel_launch(void* const* d_in, const int* in_sizes, int n_in,
                              void* d_out, int out_size, void* d_ws, size_t ws_size,
                              hipStream_t stream) {
    const float* scores  = (const float*)d_in[0];   // (1,18,100,100)
    const float* bbox    = (const float*)d_in[1];   // (1,36,100,100)
    const float* im_info = (const float*)d_in[2];   // (3,)
    float* out = (float*)d_out;                     // 300*5 rows then 90000*4 anchors

    // workspace layout
    u64*    keys  = (u64*)d_ws;                                      // 65536 B
    float4* boxes = (float4*)((char*)d_ws + PADN * sizeof(u64));     // 96000 B
    u32*    meta  = (u32*)((char*)d_ws + PADN * sizeof(u64) + PRE_TOPN * 16);
    const size_t m_off = 163840;                                     // 4KB-aligned
    u64*    M     = (u64*)((char*)d_ws + m_off);                     // 4,512,000 B
    const size_t need = m_off + (size_t)PRE_TOPN * NWORD * sizeof(u64);

    k_hist<<<1, 1024, 0, stream>>>(scores, keys, meta, out);
    k_anchors<<<(NANCH + 255) / 256, 256, 0, stream>>>((float4*)(out + POST_TOPN * 5));
    k_compact<<<(NANCH + 255) / 256, 256, 0, stream>>>(scores, meta, keys);
    k_sortboxes<<<1, 1024, 0, stream>>>(keys, bbox, im_info, boxes);
    if (ws_size >= need) {
        dim3 g(NWORD, NWORD);
        k_iou<<<g, 64, 0, stream>>>(boxes, M);
        k_scan<<<1, 128, 0, stream>>>(M, boxes, out);
    } else {
        k_nms<<<1, 1024, 0, stream>>>(boxes, out);
    }
}

// Round 3
// 171.636 us; speedup vs baseline: 2.8270x; 1.4412x over previous
//
#include <hip/hip_runtime.h>
#include <hip/hip_bf16.h>

// CreateProposal (Faster-RCNN proposal layer), H=W=100, 9 anchors, stride 16.
// Pipeline:
//   k_hist        (1 block) : score-bit histogram -> bit threshold for ~top-6000
//   k_anchors     (grid)    : write all 90000 anchors (exact ints)
//   k_compact     (grid)    : compact candidate keys (score_bits<<32 | ~idx)
//   k_locsort     (8 blks)  : each block bitonic-sorts a 1024-key segment desc
//   k_rank_decode (grid)    : exact global rank via 7 binary searches; decode
//                             + clip box straight into boxes[rank] (top-6000)
//   k_iou         (grid)    : pairwise suppression bitmap M[6000][94] (j>i)
//   k_scan        (1 block) : sequential greedy scan over bitmap, early-exit 300

#define W100 100
#define HW10K 10000
#define NANCH 90000
#define PRE_TOPN 6000
#define POST_TOPN 300
#define PADN 8192
#define NLIST 8            // 8 sorted sublists of 1024
#define LISTN 1024
#define NWORD 94           // ceil(6000/64)
#define NMS_TH 0.7f

typedef unsigned long long u64;
typedef unsigned u32;

__constant__ float c_anch[9][4] = {
    {-84.f,  -40.f,  99.f,  55.f},
    {-176.f, -88.f,  191.f, 103.f},
    {-360.f, -184.f, 375.f, 199.f},
    {-56.f,  -56.f,  71.f,  71.f},
    {-120.f, -120.f, 135.f, 135.f},
    {-248.f, -248.f, 263.f, 263.f},
    {-36.f,  -80.f,  51.f,  95.f},
    {-80.f,  -168.f, 95.f,  183.f},
    {-168.f, -344.f, 183.f, 359.f}
};

// ---------------- histogram + threshold (single block, 1024 thr) -------------
__global__ __launch_bounds__(1024)
void k_hist(const float* __restrict__ scores, u64* __restrict__ keys,
            u32* __restrict__ meta, float* __restrict__ out) {
    __shared__ u32 hist[8192];
    __shared__ u32 gsum[1024];
    const int tid = threadIdx.x;

    for (int i = tid; i < 8192; i += 1024) hist[i] = 0u;
    __syncthreads();

    const float* fg = scores + 9 * HW10K;
    for (int i = tid; i < NANCH; i += 1024) {
        u32 b = __float_as_uint(fg[i]);
        atomicAdd(&hist[b >> 17], 1u);
    }
    __syncthreads();

    u32 gs = 0;
#pragma unroll
    for (int b = 0; b < 8; ++b) gs += hist[tid * 8 + b];
    gsum[tid] = gs;
    __syncthreads();
    for (int d = 1; d < 1024; d <<= 1) {
        u32 add = (tid + d < 1024) ? gsum[tid + d] : 0u;
        __syncthreads();
        gsum[tid] += add;
        __syncthreads();
    }
    u32 nxt = (tid < 1023) ? gsum[tid + 1] : 0u;
    if (gsum[tid] >= (u32)PRE_TOPN && nxt < (u32)PRE_TOPN) {
        u32 run = nxt;
        u32 T = (u32)tid * 8u;
        for (int b = 7; b >= 0; --b) {
            run += hist[tid * 8 + b];
            if (run >= (u32)PRE_TOPN) { T = (u32)tid * 8u + (u32)b; break; }
        }
        meta[1] = T << 17;
        meta[0] = 0u;
    }

    for (int i = tid; i < PADN; i += 1024) keys[i] = 0ull;
    for (int i = tid; i < POST_TOPN * 5; i += 1024) out[i] = 0.f;
}

// ---------------- anchors output (exact) -------------------------------------
__global__ void k_anchors(float4* __restrict__ anc_out) {
    int idx = blockIdx.x * blockDim.x + threadIdx.x;
    if (idx >= NANCH) return;
    int a = idx % 9, pos = idx / 9;
    int y = pos / W100, x = pos - y * W100;
    float sx = (float)(x * 16), sy = (float)(y * 16);
    anc_out[idx] = make_float4(c_anch[a][0] + sx, c_anch[a][1] + sy,
                               c_anch[a][2] + sx, c_anch[a][3] + sy);
}

// ---------------- compact candidates -----------------------------------------
__global__ void k_compact(const float* __restrict__ scores, u32* __restrict__ meta,
                          u64* __restrict__ keys) {
    int idx = blockIdx.x * blockDim.x + threadIdx.x;
    if (idx >= NANCH) return;
    int pos = idx / 9;
    int a = idx - pos * 9;
    u32 bits = __float_as_uint(scores[(9 + a) * HW10K + pos]);
    if (bits >= meta[1]) {
        u32 slot = atomicAdd(&meta[0], 1u);
        if (slot < (u32)PADN)
            keys[slot] = ((u64)bits << 32) | (u32)(~(u32)idx);
    }
}

// ---------------- per-segment bitonic sort (8 blocks x 512 thr) --------------
__global__ __launch_bounds__(512)
void k_locsort(u64* __restrict__ keys) {
    __shared__ u64 s[LISTN];
    const int tid = threadIdx.x;
    u64* seg = keys + (size_t)blockIdx.x * LISTN;
    for (int i = tid; i < LISTN; i += 512) s[i] = seg[i];
    __syncthreads();

    for (u32 k = 2; k <= (u32)LISTN; k <<= 1) {
        for (u32 j = k >> 1; j > 0; j >>= 1) {
            u32 p  = (u32)tid;                 // one compare per thread
            u32 i  = 2u * p - (p & (j - 1u));
            u32 ix = i | j;
            u64 A = s[i], B = s[ix];
            bool asc = (i & k) != 0u;          // overall DESCENDING sort
            bool sw  = asc ? (A > B) : (A < B);
            if (sw) { s[i] = B; s[ix] = A; }
            __syncthreads();
        }
    }
    for (int i = tid; i < LISTN; i += 512) seg[i] = s[i];
}

// ---------------- global rank via binary searches + decode -------------------
__global__ __launch_bounds__(256)
void k_rank_decode(const u64* __restrict__ keys, const float* __restrict__ bbox,
                   const float* __restrict__ im_info, float4* __restrict__ boxes) {
    const int g = blockIdx.x * blockDim.x + threadIdx.x;
    if (g >= PADN) return;
    const u64 e = keys[g];
    if (e == 0ull) return;                     // pad: rank >= C >= 6000
    const int l = g >> 10;                     // own list
    int rank = g & (LISTN - 1);                // position in own (desc) list
#pragma unroll
    for (int l2 = 0; l2 < NLIST; ++l2) {
        if (l2 == l) continue;
        const u64* lst = keys + (size_t)l2 * LISTN;
        int lo = 0, hi = LISTN;                // count of elements > e
        while (lo < hi) {
            int mid = (lo + hi) >> 1;
            if (lst[mid] > e) lo = mid + 1; else hi = mid;
        }
        rank += lo;
    }
    if (rank >= PRE_TOPN) return;

    const u32 idx = ~((u32)e);
    int pos = (int)(idx / 9u);
    int a   = (int)(idx - (u32)pos * 9u);
    int y = pos / W100, x = pos - y * W100;
    float sx = (float)(x * 16), sy = (float)(y * 16);
    float ax1 = c_anch[a][0] + sx, ay1 = c_anch[a][1] + sy;
    float ax2 = c_anch[a][2] + sx, ay2 = c_anch[a][3] + sy;
    float w = ax2 - ax1 + 1.f, h = ay2 - ay1 + 1.f;
    float cx = ax1 + 0.5f * w,  cy = ay1 + 0.5f * h;
    float dx = bbox[(a * 4 + 0) * HW10K + pos];
    float dy = bbox[(a * 4 + 1) * HW10K + pos];
    float dw = bbox[(a * 4 + 2) * HW10K + pos];
    float dh = bbox[(a * 4 + 3) * HW10K + pos];
    float pcx = dx * w + cx, pcy = dy * h + cy;
    float pw = expf(dw) * w, ph = expf(dh) * h;
    float imH = im_info[0], imW = im_info[1];
    float x1 = pcx - 0.5f * pw, y1 = pcy - 0.5f * ph;
    float x2 = pcx + 0.5f * pw, y2 = pcy + 0.5f * ph;
    x1 = fminf(fmaxf(x1, 0.f), imW - 1.f);
    x2 = fminf(fmaxf(x2, 0.f), imW - 1.f);
    y1 = fminf(fmaxf(y1, 0.f), imH - 1.f);
    y2 = fminf(fmaxf(y2, 0.f), imH - 1.f);
    boxes[rank] = make_float4(x1, y1, x2, y2);
}

// ---------------- pairwise suppression bitmap (grid) -------------------------
// M[i][w] bit k = ( IoU(box i, box 64w+k) > TH ) && (64w+k > i), upper tri only.
__global__ __launch_bounds__(64)
void k_iou(const float4* __restrict__ bx, u64* __restrict__ M) {
    const int rb = blockIdx.y, cb = blockIdx.x;
    if (cb < rb) return;
    __shared__ float4 cbox[64];
    const int tid = threadIdx.x;
    const int col0 = cb * 64;
    {
        int cj = col0 + tid;
        cbox[tid] = (cj < PRE_TOPN) ? bx[cj] : make_float4(0.f, 0.f, -2.f, -2.f);
    }
    __syncthreads();
    const int ri = rb * 64 + tid;
    if (ri >= PRE_TOPN) return;
    float4 b = bx[ri];
    float area = (b.z - b.x + 1.f) * (b.w - b.y + 1.f);
    u64 bits = 0ull;
    const int ncol = (col0 + 64 <= PRE_TOPN) ? 64 : (PRE_TOPN - col0);
#pragma unroll 8
    for (int k = 0; k < 64; ++k) {
        if (k >= ncol) break;
        float4 q = cbox[k];
        float qa = (q.z - q.x + 1.f) * (q.w - q.y + 1.f);
        float iw = fmaxf(fminf(b.z, q.z) - fmaxf(b.x, q.x) + 1.f, 0.f);
        float ih = fmaxf(fminf(b.w, q.w) - fmaxf(b.y, q.y) + 1.f, 0.f);
        float inter = iw * ih;
        float iou = inter / ((area + qa) - inter);
        if ((col0 + k > ri) && (iou > NMS_TH)) bits |= (1ull << k);
    }
    M[(size_t)ri * NWORD + cb] = bits;
}

// ---------------- sequential greedy scan over bitmap (1 block, 128 thr) ------
__global__ __launch_bounds__(128)
void k_scan(const u64* __restrict__ M, const float4* __restrict__ bx,
            float* __restrict__ out) {
    __shared__ u64 supp[NWORD];
    __shared__ u64 s_kept;
    __shared__ int s_rank;
    const int tid = threadIdx.x;
    if (tid < NWORD) supp[tid] = 0ull;
    if (tid == 0) s_rank = 0;
    __syncthreads();

    for (int c = 0; c < NWORD; ++c) {
        const int base = c * 64;
        if (tid < 64) {
            const int j = base + tid;
            const bool valid = j < PRE_TOPN;
            u64 m = valid ? M[(size_t)j * NWORD + c] : 0ull;
            float4 b = valid ? bx[j] : make_float4(0.f, 0.f, 0.f, 0.f);
            u64 alive = __ballot(valid) & ~supp[c];
            u64 kept = 0ull;
            while (alive) {
                int k = (int)__builtin_ctzll(alive);
                kept |= (1ull << k);
                u32 mlo = (u32)__builtin_amdgcn_readlane((int)(u32)m, k);
                u32 mhi = (u32)__builtin_amdgcn_readlane((int)(u32)(m >> 32), k);
                u64 mk = ((u64)mhi << 32) | mlo;
                alive &= ~mk;
                alive &= ~(1ull << k);
            }
            int r0 = s_rank;                 // read before lane-0 update (in-order wave)
            if (valid && ((kept >> tid) & 1ull)) {
                int r = r0 + (int)__popcll(kept & ((1ull << tid) - 1ull));
                if (r < POST_TOPN) {
                    out[r * 5 + 0] = 0.f;
                    out[r * 5 + 1] = b.x; out[r * 5 + 2] = b.y;
                    out[r * 5 + 3] = b.z; out[r * 5 + 4] = b.w;
                }
            }
            if (tid == 0) { s_kept = kept; s_rank = r0 + (int)__popcll(kept); }
        }
        __syncthreads();
        if (s_rank >= POST_TOPN) break;      // uniform
        const u64 kept = s_kept;
        if (kept) {
            for (int w = c + 1 + tid; w < NWORD; w += 128) {
                u64 acc = supp[w];
                u64 t = kept;
                while (t) {
                    int k = (int)__builtin_ctzll(t);
                    t &= t - 1ull;
                    acc |= M[(size_t)(base + k) * NWORD + w];
                }
                supp[w] = acc;
            }
        }
        __syncthreads();
    }
}

// ---------------- launch ------------------------------------------------------
extern "C" void kernel_launch(void* const* d_in, const int* in_sizes, int n_in,
                              void* d_out, int out_size, void* d_ws, size_t ws_size,
                              hipStream_t stream) {
    const float* scores  = (const float*)d_in[0];   // (1,18,100,100)
    const float* bbox    = (const float*)d_in[1];   // (1,36,100,100)
    const float* im_info = (const float*)d_in[2];   // (3,)
    float* out = (float*)d_out;                     // 300*5 rows then 90000*4 anchors

    // workspace layout
    u64*    keys  = (u64*)d_ws;                                      // 65536 B
    float4* boxes = (float4*)((char*)d_ws + PADN * sizeof(u64));     // 96000 B
    u32*    meta  = (u32*)((char*)d_ws + PADN * sizeof(u64) + PRE_TOPN * 16);
    const size_t m_off = 163840;                                     // 4KB-aligned
    u64*    M     = (u64*)((char*)d_ws + m_off);                     // 4,512,000 B

    k_hist<<<1, 1024, 0, stream>>>(scores, keys, meta, out);
    k_anchors<<<(NANCH + 255) / 256, 256, 0, stream>>>((float4*)(out + POST_TOPN * 5));
    k_compact<<<(NANCH + 255) / 256, 256, 0, stream>>>(scores, meta, keys);
    k_locsort<<<NLIST, 512, 0, stream>>>(keys);
    k_rank_decode<<<PADN / 256, 256, 0, stream>>>(keys, bbox, im_info, boxes);
    dim3 g(NWORD, NWORD);
    k_iou<<<g, 64, 0, stream>>>(boxes, M);
    k_scan<<<1, 128, 0, stream>>>(M, boxes, out);
}

// Round 4
// 126.720 us; speedup vs baseline: 3.8290x; 1.3545x over previous
//
#include <hip/hip_runtime.h>
#include <hip/hip_bf16.h>

// CreateProposal (Faster-RCNN proposal layer), H=W=100, 9 anchors, stride 16.
// Pipeline:
//   k_hist        (1 block) : score-bit histogram -> bit threshold for ~top-6000
//   k_anchors     (grid)    : write all 90000 anchors (exact ints)
//   k_compact     (grid)    : compact candidate keys (score_bits<<32 | ~idx)
//   k_locsort     (8 blks)  : each block bitonic-sorts a 1024-key segment desc
//   k_rank_decode (grid)    : exact global rank via 7 binary searches; decode
//                             + clip box straight into boxes[rank] (top-6000)
//   k_iou         (grid)    : pairwise suppression bitmap M[6000][94] (j>i)
//   k_scan        (1 block) : greedy scan; diag preloaded in LDS, supp update
//                             parallelized over (word,keptbox) pairs

#define W100 100
#define HW10K 10000
#define NANCH 90000
#define PRE_TOPN 6000
#define POST_TOPN 300
#define PADN 8192
#define NLIST 8            // 8 sorted sublists of 1024
#define LISTN 1024
#define NWORD 94           // ceil(6000/64)
#define NMS_TH 0.7f

typedef unsigned long long u64;
typedef unsigned u32;

__constant__ float c_anch[9][4] = {
    {-84.f,  -40.f,  99.f,  55.f},
    {-176.f, -88.f,  191.f, 103.f},
    {-360.f, -184.f, 375.f, 199.f},
    {-56.f,  -56.f,  71.f,  71.f},
    {-120.f, -120.f, 135.f, 135.f},
    {-248.f, -248.f, 263.f, 263.f},
    {-36.f,  -80.f,  51.f,  95.f},
    {-80.f,  -168.f, 95.f,  183.f},
    {-168.f, -344.f, 183.f, 359.f}
};

// ---------------- histogram + threshold (single block, 1024 thr) -------------
__global__ __launch_bounds__(1024)
void k_hist(const float* __restrict__ scores, u64* __restrict__ keys,
            u32* __restrict__ meta, float* __restrict__ out) {
    __shared__ u32 hist[8192];
    __shared__ u32 gsum[1024];
    const int tid = threadIdx.x;

    for (int i = tid; i < 8192; i += 1024) hist[i] = 0u;
    __syncthreads();

    const float* fg = scores + 9 * HW10K;
    for (int i = tid; i < NANCH; i += 1024) {
        u32 b = __float_as_uint(fg[i]);
        atomicAdd(&hist[b >> 17], 1u);
    }
    __syncthreads();

    u32 gs = 0;
#pragma unroll
    for (int b = 0; b < 8; ++b) gs += hist[tid * 8 + b];
    gsum[tid] = gs;
    __syncthreads();
    for (int d = 1; d < 1024; d <<= 1) {
        u32 add = (tid + d < 1024) ? gsum[tid + d] : 0u;
        __syncthreads();
        gsum[tid] += add;
        __syncthreads();
    }
    u32 nxt = (tid < 1023) ? gsum[tid + 1] : 0u;
    if (gsum[tid] >= (u32)PRE_TOPN && nxt < (u32)PRE_TOPN) {
        u32 run = nxt;
        u32 T = (u32)tid * 8u;
        for (int b = 7; b >= 0; --b) {
            run += hist[tid * 8 + b];
            if (run >= (u32)PRE_TOPN) { T = (u32)tid * 8u + (u32)b; break; }
        }
        meta[1] = T << 17;
        meta[0] = 0u;
    }

    for (int i = tid; i < PADN; i += 1024) keys[i] = 0ull;
    for (int i = tid; i < POST_TOPN * 5; i += 1024) out[i] = 0.f;
}

// ---------------- anchors output (exact) -------------------------------------
__global__ void k_anchors(float4* __restrict__ anc_out) {
    int idx = blockIdx.x * blockDim.x + threadIdx.x;
    if (idx >= NANCH) return;
    int a = idx % 9, pos = idx / 9;
    int y = pos / W100, x = pos - y * W100;
    float sx = (float)(x * 16), sy = (float)(y * 16);
    anc_out[idx] = make_float4(c_anch[a][0] + sx, c_anch[a][1] + sy,
                               c_anch[a][2] + sx, c_anch[a][3] + sy);
}

// ---------------- compact candidates -----------------------------------------
__global__ void k_compact(const float* __restrict__ scores, u32* __restrict__ meta,
                          u64* __restrict__ keys) {
    int idx = blockIdx.x * blockDim.x + threadIdx.x;
    if (idx >= NANCH) return;
    int pos = idx / 9;
    int a = idx - pos * 9;
    u32 bits = __float_as_uint(scores[(9 + a) * HW10K + pos]);
    if (bits >= meta[1]) {
        u32 slot = atomicAdd(&meta[0], 1u);
        if (slot < (u32)PADN)
            keys[slot] = ((u64)bits << 32) | (u32)(~(u32)idx);
    }
}

// ---------------- per-segment bitonic sort (8 blocks x 512 thr) --------------
__global__ __launch_bounds__(512)
void k_locsort(u64* __restrict__ keys) {
    __shared__ u64 s[LISTN];
    const int tid = threadIdx.x;
    u64* seg = keys + (size_t)blockIdx.x * LISTN;
    for (int i = tid; i < LISTN; i += 512) s[i] = seg[i];
    __syncthreads();

    for (u32 k = 2; k <= (u32)LISTN; k <<= 1) {
        for (u32 j = k >> 1; j > 0; j >>= 1) {
            u32 p  = (u32)tid;                 // one compare per thread
            u32 i  = 2u * p - (p & (j - 1u));
            u32 ix = i | j;
            u64 A = s[i], B = s[ix];
            bool asc = (i & k) != 0u;          // overall DESCENDING sort
            bool sw  = asc ? (A > B) : (A < B);
            if (sw) { s[i] = B; s[ix] = A; }
            __syncthreads();
        }
    }
    for (int i = tid; i < LISTN; i += 512) seg[i] = s[i];
}

// ---------------- global rank via binary searches + decode -------------------
__global__ __launch_bounds__(256)
void k_rank_decode(const u64* __restrict__ keys, const float* __restrict__ bbox,
                   const float* __restrict__ im_info, float4* __restrict__ boxes) {
    const int g = blockIdx.x * blockDim.x + threadIdx.x;
    if (g >= PADN) return;
    const u64 e = keys[g];
    if (e == 0ull) return;                     // pad: rank >= C >= 6000
    const int l = g >> 10;                     // own list
    int rank = g & (LISTN - 1);                // position in own (desc) list
#pragma unroll
    for (int l2 = 0; l2 < NLIST; ++l2) {
        if (l2 == l) continue;
        const u64* lst = keys + (size_t)l2 * LISTN;
        int lo = 0, hi = LISTN;                // count of elements > e
        while (lo < hi) {
            int mid = (lo + hi) >> 1;
            if (lst[mid] > e) lo = mid + 1; else hi = mid;
        }
        rank += lo;
    }
    if (rank >= PRE_TOPN) return;

    const u32 idx = ~((u32)e);
    int pos = (int)(idx / 9u);
    int a   = (int)(idx - (u32)pos * 9u);
    int y = pos / W100, x = pos - y * W100;
    float sx = (float)(x * 16), sy = (float)(y * 16);
    float ax1 = c_anch[a][0] + sx, ay1 = c_anch[a][1] + sy;
    float ax2 = c_anch[a][2] + sx, ay2 = c_anch[a][3] + sy;
    float w = ax2 - ax1 + 1.f, h = ay2 - ay1 + 1.f;
    float cx = ax1 + 0.5f * w,  cy = ay1 + 0.5f * h;
    float dx = bbox[(a * 4 + 0) * HW10K + pos];
    float dy = bbox[(a * 4 + 1) * HW10K + pos];
    float dw = bbox[(a * 4 + 2) * HW10K + pos];
    float dh = bbox[(a * 4 + 3) * HW10K + pos];
    float pcx = dx * w + cx, pcy = dy * h + cy;
    float pw = expf(dw) * w, ph = expf(dh) * h;
    float imH = im_info[0], imW = im_info[1];
    float x1 = pcx - 0.5f * pw, y1 = pcy - 0.5f * ph;
    float x2 = pcx + 0.5f * pw, y2 = pcy + 0.5f * ph;
    x1 = fminf(fmaxf(x1, 0.f), imW - 1.f);
    x2 = fminf(fmaxf(x2, 0.f), imW - 1.f);
    y1 = fminf(fmaxf(y1, 0.f), imH - 1.f);
    y2 = fminf(fmaxf(y2, 0.f), imH - 1.f);
    boxes[rank] = make_float4(x1, y1, x2, y2);
}

// ---------------- pairwise suppression bitmap (grid) -------------------------
// M[i][w] bit k = ( IoU(box i, box 64w+k) > TH ) && (64w+k > i), upper tri only.
__global__ __launch_bounds__(64)
void k_iou(const float4* __restrict__ bx, u64* __restrict__ M) {
    const int rb = blockIdx.y, cb = blockIdx.x;
    if (cb < rb) return;
    __shared__ float4 cbox[64];
    const int tid = threadIdx.x;
    const int col0 = cb * 64;
    {
        int cj = col0 + tid;
        cbox[tid] = (cj < PRE_TOPN) ? bx[cj] : make_float4(0.f, 0.f, -2.f, -2.f);
    }
    __syncthreads();
    const int ri = rb * 64 + tid;
    if (ri >= PRE_TOPN) return;
    float4 b = bx[ri];
    float area = (b.z - b.x + 1.f) * (b.w - b.y + 1.f);
    u64 bits = 0ull;
    const int ncol = (col0 + 64 <= PRE_TOPN) ? 64 : (PRE_TOPN - col0);
#pragma unroll 8
    for (int k = 0; k < 64; ++k) {
        if (k >= ncol) break;
        float4 q = cbox[k];
        float qa = (q.z - q.x + 1.f) * (q.w - q.y + 1.f);
        float iw = fmaxf(fminf(b.z, q.z) - fmaxf(b.x, q.x) + 1.f, 0.f);
        float ih = fmaxf(fminf(b.w, q.w) - fmaxf(b.y, q.y) + 1.f, 0.f);
        float inter = iw * ih;
        float iou = inter / ((area + qa) - inter);
        if ((col0 + k > ri) && (iou > NMS_TH)) bits |= (1ull << k);
    }
    M[(size_t)ri * NWORD + cb] = bits;
}

// ---------------- greedy scan over bitmap (1 block, 1024 thr) ----------------
// diag[c][j] preloaded in LDS; supp update parallel over (word, keptbox) pairs.
__global__ __launch_bounds__(1024)
void k_scan(const u64* __restrict__ M, const float4* __restrict__ bx,
            float* __restrict__ out) {
    __shared__ u64 diag[NWORD * 64];     // 48128 B
    __shared__ u64 supp[NWORD];
    __shared__ int s_newkept[64];
    __shared__ int s_nk, s_rank;
    const int tid = threadIdx.x;

    for (int i = tid; i < NWORD * 64; i += 1024) {
        int c = i >> 6, j = i & 63;
        int row = c * 64 + j;
        diag[i] = (row < PRE_TOPN) ? M[(size_t)row * NWORD + c] : 0ull;
    }
    if (tid < NWORD) supp[tid] = 0ull;
    if (tid == 0) s_rank = 0;
    __syncthreads();

    for (int c = 0; c < NWORD; ++c) {
        const int base = c * 64;
        if (tid < 64) {                      // wave 0: chase
            const int j = base + tid;
            const bool valid = j < PRE_TOPN;
            u64 m = diag[base + tid];        // (base+tid) == c*64+tid == flat index
            u64 alive = __ballot(valid) & ~supp[c];
            u64 kept = 0ull;
            while (alive) {
                int k = (int)__builtin_ctzll(alive);
                kept |= (1ull << k);
                u32 mlo = (u32)__builtin_amdgcn_readlane((int)(u32)m, k);
                u32 mhi = (u32)__builtin_amdgcn_readlane((int)(u32)(m >> 32), k);
                u64 mk = ((u64)mhi << 32) | mlo;
                alive &= ~mk;
                alive &= ~(1ull << k);
            }
            int r0 = s_rank;                 // read before lane-0 update (in-order wave)
            if (valid && ((kept >> tid) & 1ull)) {
                int rin = (int)__popcll(kept & ((1ull << tid) - 1ull));
                s_newkept[rin] = j;
                int r = r0 + rin;
                if (r < POST_TOPN) {
                    float4 b = bx[j];
                    out[r * 5 + 0] = 0.f;
                    out[r * 5 + 1] = b.x; out[r * 5 + 2] = b.y;
                    out[r * 5 + 3] = b.z; out[r * 5 + 4] = b.w;
                }
            }
            if (tid == 0) { s_nk = (int)__popcll(kept); s_rank = r0 + (int)__popcll(kept); }
        }
        __syncthreads();
        if (s_rank >= POST_TOPN) break;      // uniform
        const int nk = s_nk;
        const int nw = NWORD - 1 - c;
        if (nk > 0 && nw > 0) {
            const int total = nw * nk;       // one load + one LDS atomicOr per pair
            for (int p = tid; p < total; p += 1024) {
                int w = c + 1 + p / nk;
                int k = p - nk * (p / nk);
                int j = s_newkept[k];
                u64 row = M[(size_t)j * NWORD + w];
                if (row) atomicOr(&supp[w], row);
            }
        }
        __syncthreads();
    }
}

// ---------------- launch ------------------------------------------------------
extern "C" void kernel_launch(void* const* d_in, const int* in_sizes, int n_in,
                              void* d_out, int out_size, void* d_ws, size_t ws_size,
                              hipStream_t stream) {
    const float* scores  = (const float*)d_in[0];   // (1,18,100,100)
    const float* bbox    = (const float*)d_in[1];   // (1,36,100,100)
    const float* im_info = (const float*)d_in[2];   // (3,)
    float* out = (float*)d_out;                     // 300*5 rows then 90000*4 anchors

    // workspace layout
    u64*    keys  = (u64*)d_ws;                                      // 65536 B
    float4* boxes = (float4*)((char*)d_ws + PADN * sizeof(u64));     // 96000 B
    u32*    meta  = (u32*)((char*)d_ws + PADN * sizeof(u64) + PRE_TOPN * 16);
    const size_t m_off = 163840;                                     // 4KB-aligned
    u64*    M     = (u64*)((char*)d_ws + m_off);                     // 4,512,000 B

    k_hist<<<1, 1024, 0, stream>>>(scores, keys, meta, out);
    k_anchors<<<(NANCH + 255) / 256, 256, 0, stream>>>((float4*)(out + POST_TOPN * 5));
    k_compact<<<(NANCH + 255) / 256, 256, 0, stream>>>(scores, meta, keys);
    k_locsort<<<NLIST, 512, 0, stream>>>(keys);
    k_rank_decode<<<PADN / 256, 256, 0, stream>>>(keys, bbox, im_info, boxes);
    dim3 g(NWORD, NWORD);
    k_iou<<<g, 64, 0, stream>>>(boxes, M);
    k_scan<<<1, 1024, 0, stream>>>(M, boxes, out);
}

// Round 5
// 112.908 us; speedup vs baseline: 4.2974x; 1.1223x over previous
//
#include <hip/hip_runtime.h>
#include <hip/hip_bf16.h>

// CreateProposal (Faster-RCNN proposal layer), H=W=100, 9 anchors, stride 16.
// Pipeline:
//   k_anchors_zero (grid)   : write all 90000 anchors; zero hist/keys/out-head
//   k_hist_grid    (45 blk) : per-block LDS histogram -> global 8192-bin hist
//   k_thresh       (1 blk)  : wave-scan suffix of hist -> bit threshold ~top-6000
//   k_compact      (grid)   : compact candidate keys (score_bits<<32 | ~idx)
//   k_locsort      (8 blk)  : each block bitonic-sorts a 1024-key segment desc
//   k_rank_decode  (grid)   : exact global rank via 7 binary searches; decode
//                             + clip box straight into boxes[rank] (top-6000)
//   k_iou          (grid)   : pairwise suppression bitmap M[6000][94] (j>i)
//   k_scan         (1 blk)  : greedy scan; diag in LDS, parallel supp update

#define W100 100
#define HW10K 10000
#define NANCH 90000
#define PRE_TOPN 6000
#define POST_TOPN 300
#define PADN 8192
#define NLIST 8            // 8 sorted sublists of 1024
#define LISTN 1024
#define NWORD 94           // ceil(6000/64)
#define NMS_TH 0.7f

typedef unsigned long long u64;
typedef unsigned u32;

__constant__ float c_anch[9][4] = {
    {-84.f,  -40.f,  99.f,  55.f},
    {-176.f, -88.f,  191.f, 103.f},
    {-360.f, -184.f, 375.f, 199.f},
    {-56.f,  -56.f,  71.f,  71.f},
    {-120.f, -120.f, 135.f, 135.f},
    {-248.f, -248.f, 263.f, 263.f},
    {-36.f,  -80.f,  51.f,  95.f},
    {-80.f,  -168.f, 95.f,  183.f},
    {-168.f, -344.f, 183.f, 359.f}
};

// -------- anchors output (exact) + zero hist/keys/out-head -------------------
__global__ void k_anchors_zero(float4* __restrict__ anc_out, u32* __restrict__ hist,
                               u64* __restrict__ keys, float* __restrict__ out) {
    int idx = blockIdx.x * blockDim.x + threadIdx.x;
    if (idx < 8192) { hist[idx] = 0u; keys[idx] = 0ull; }
    if (idx < POST_TOPN * 5) out[idx] = 0.f;
    if (idx >= NANCH) return;
    int a = idx % 9, pos = idx / 9;
    int y = pos / W100, x = pos - y * W100;
    float sx = (float)(x * 16), sy = (float)(y * 16);
    anc_out[idx] = make_float4(c_anch[a][0] + sx, c_anch[a][1] + sy,
                               c_anch[a][2] + sx, c_anch[a][3] + sy);
}

// -------- grid histogram: per-block LDS hist, flush nonzero bins -------------
__global__ __launch_bounds__(1024)
void k_hist_grid(const float* __restrict__ scores, u32* __restrict__ hist) {
    __shared__ u32 lh[8192];
    const int tid = threadIdx.x;
    for (int i = tid; i < 8192; i += 1024) lh[i] = 0u;
    __syncthreads();

    const float4* fg4 = (const float4*)(scores + 9 * HW10K);  // 22500 float4
    if (tid < 500) {
        float4 v = fg4[blockIdx.x * 500 + tid];               // 45*500 = 22500
        atomicAdd(&lh[__float_as_uint(v.x) >> 17], 1u);
        atomicAdd(&lh[__float_as_uint(v.y) >> 17], 1u);
        atomicAdd(&lh[__float_as_uint(v.z) >> 17], 1u);
        atomicAdd(&lh[__float_as_uint(v.w) >> 17], 1u);
    }
    __syncthreads();
    for (int i = tid; i < 8192; i += 1024) {
        u32 c = lh[i];
        if (c) atomicAdd(&hist[i], c);
    }
}

// -------- threshold from suffix scan of hist (1 block, wave shuffles) --------
__global__ __launch_bounds__(1024)
void k_thresh(const u32* __restrict__ hist, u32* __restrict__ meta) {
    __shared__ u32 wsum_s[16];
    __shared__ u32 wtail_s[16];
    const int tid = threadIdx.x;
    const int w = tid >> 6, lane = tid & 63;

    const uint4* h4 = (const uint4*)hist;
    uint4 A = h4[tid * 2], B = h4[tid * 2 + 1];
    u32 h[8] = {A.x, A.y, A.z, A.w, B.x, B.y, B.z, B.w};
    u32 gs = h[0] + h[1] + h[2] + h[3] + h[4] + h[5] + h[6] + h[7];

    u32 suf = gs;                         // suffix sum within wave (lanes >= lane)
#pragma unroll
    for (int d = 1; d < 64; d <<= 1) {
        u32 t = (u32)__shfl((int)suf, (lane + d) & 63);
        suf += (lane + d < 64) ? t : 0u;
    }
    if (lane == 0) wsum_s[w] = suf;       // wave total
    __syncthreads();
    if (w == 0) {
        u32 v = (lane < 16) ? wsum_s[lane] : 0u;
        u32 s2 = v;
#pragma unroll
        for (int d = 1; d < 16; d <<= 1) {
            u32 t = (u32)__shfl((int)s2, (lane + d) & 63);
            s2 += (lane + d < 16) ? t : 0u;
        }
        if (lane < 16) wtail_s[lane] = s2 - v;   // sum over waves > w
    }
    __syncthreads();

    u32 S = suf + wtail_s[w];             // sum over tid' >= tid
    if (S >= (u32)PRE_TOPN && S - gs < (u32)PRE_TOPN) {
        u32 run = S - gs;
        u32 T = (u32)tid * 8u;
        for (int b = 7; b >= 0; --b) {
            run += h[b];
            if (run >= (u32)PRE_TOPN) { T = (u32)tid * 8u + (u32)b; break; }
        }
        meta[1] = T << 17;                // admit all score_bits >= meta[1]
        meta[0] = 0u;                     // compact counter
    }
}

// ---------------- compact candidates -----------------------------------------
__global__ void k_compact(const float* __restrict__ scores, u32* __restrict__ meta,
                          u64* __restrict__ keys) {
    int idx = blockIdx.x * blockDim.x + threadIdx.x;
    if (idx >= NANCH) return;
    int pos = idx / 9;
    int a = idx - pos * 9;
    u32 bits = __float_as_uint(scores[(9 + a) * HW10K + pos]);
    if (bits >= meta[1]) {
        u32 slot = atomicAdd(&meta[0], 1u);
        if (slot < (u32)PADN)
            keys[slot] = ((u64)bits << 32) | (u32)(~(u32)idx);
    }
}

// ---------------- per-segment bitonic sort (8 blocks x 512 thr) --------------
__global__ __launch_bounds__(512)
void k_locsort(u64* __restrict__ keys) {
    __shared__ u64 s[LISTN];
    const int tid = threadIdx.x;
    u64* seg = keys + (size_t)blockIdx.x * LISTN;
    for (int i = tid; i < LISTN; i += 512) s[i] = seg[i];
    __syncthreads();

    for (u32 k = 2; k <= (u32)LISTN; k <<= 1) {
        for (u32 j = k >> 1; j > 0; j >>= 1) {
            u32 p  = (u32)tid;                 // one compare per thread
            u32 i  = 2u * p - (p & (j - 1u));
            u32 ix = i | j;
            u64 A = s[i], B = s[ix];
            bool asc = (i & k) != 0u;          // overall DESCENDING sort
            bool sw  = asc ? (A > B) : (A < B);
            if (sw) { s[i] = B; s[ix] = A; }
            __syncthreads();
        }
    }
    for (int i = tid; i < LISTN; i += 512) seg[i] = s[i];
}

// ---------------- global rank via binary searches + decode -------------------
__global__ __launch_bounds__(256)
void k_rank_decode(const u64* __restrict__ keys, const float* __restrict__ bbox,
                   const float* __restrict__ im_info, float4* __restrict__ boxes) {
    const int g = blockIdx.x * blockDim.x + threadIdx.x;
    if (g >= PADN) return;
    const u64 e = keys[g];
    if (e == 0ull) return;                     // pad: rank >= C >= 6000
    const int l = g >> 10;                     // own list
    int rank = g & (LISTN - 1);                // position in own (desc) list
#pragma unroll
    for (int l2 = 0; l2 < NLIST; ++l2) {
        if (l2 == l) continue;
        const u64* lst = keys + (size_t)l2 * LISTN;
        int lo = 0, hi = LISTN;                // count of elements > e
        while (lo < hi) {
            int mid = (lo + hi) >> 1;
            if (lst[mid] > e) lo = mid + 1; else hi = mid;
        }
        rank += lo;
    }
    if (rank >= PRE_TOPN) return;

    const u32 idx = ~((u32)e);
    int pos = (int)(idx / 9u);
    int a   = (int)(idx - (u32)pos * 9u);
    int y = pos / W100, x = pos - y * W100;
    float sx = (float)(x * 16), sy = (float)(y * 16);
    float ax1 = c_anch[a][0] + sx, ay1 = c_anch[a][1] + sy;
    float ax2 = c_anch[a][2] + sx, ay2 = c_anch[a][3] + sy;
    float w = ax2 - ax1 + 1.f, h = ay2 - ay1 + 1.f;
    float cx = ax1 + 0.5f * w,  cy = ay1 + 0.5f * h;
    float dx = bbox[(a * 4 + 0) * HW10K + pos];
    float dy = bbox[(a * 4 + 1) * HW10K + pos];
    float dw = bbox[(a * 4 + 2) * HW10K + pos];
    float dh = bbox[(a * 4 + 3) * HW10K + pos];
    float pcx = dx * w + cx, pcy = dy * h + cy;
    float pw = expf(dw) * w, ph = expf(dh) * h;
    float imH = im_info[0], imW = im_info[1];
    float x1 = pcx - 0.5f * pw, y1 = pcy - 0.5f * ph;
    float x2 = pcx + 0.5f * pw, y2 = pcy + 0.5f * ph;
    x1 = fminf(fmaxf(x1, 0.f), imW - 1.f);
    x2 = fminf(fmaxf(x2, 0.f), imW - 1.f);
    y1 = fminf(fmaxf(y1, 0.f), imH - 1.f);
    y2 = fminf(fmaxf(y2, 0.f), imH - 1.f);
    boxes[rank] = make_float4(x1, y1, x2, y2);
}

// ---------------- pairwise suppression bitmap (grid) -------------------------
// M[i][w] bit k = ( IoU(box i, box 64w+k) > TH ) && (64w+k > i), upper tri only.
__global__ __launch_bounds__(64)
void k_iou(const float4* __restrict__ bx, u64* __restrict__ M) {
    const int rb = blockIdx.y, cb = blockIdx.x;
    if (cb < rb) return;
    __shared__ float4 cbox[64];
    const int tid = threadIdx.x;
    const int col0 = cb * 64;
    {
        int cj = col0 + tid;
        cbox[tid] = (cj < PRE_TOPN) ? bx[cj] : make_float4(0.f, 0.f, -2.f, -2.f);
    }
    __syncthreads();
    const int ri = rb * 64 + tid;
    if (ri >= PRE_TOPN) return;
    float4 b = bx[ri];
    float area = (b.z - b.x + 1.f) * (b.w - b.y + 1.f);
    u64 bits = 0ull;
    const int ncol = (col0 + 64 <= PRE_TOPN) ? 64 : (PRE_TOPN - col0);
#pragma unroll 8
    for (int k = 0; k < 64; ++k) {
        if (k >= ncol) break;
        float4 q = cbox[k];
        float qa = (q.z - q.x + 1.f) * (q.w - q.y + 1.f);
        float iw = fmaxf(fminf(b.z, q.z) - fmaxf(b.x, q.x) + 1.f, 0.f);
        float ih = fmaxf(fminf(b.w, q.w) - fmaxf(b.y, q.y) + 1.f, 0.f);
        float inter = iw * ih;
        float iou = inter / ((area + qa) - inter);
        if ((col0 + k > ri) && (iou > NMS_TH)) bits |= (1ull << k);
    }
    M[(size_t)ri * NWORD + cb] = bits;
}

// ---------------- greedy scan over bitmap (1 block, 1024 thr) ----------------
// diag[c][j] preloaded in LDS; supp update parallel over (word, keptbox) pairs.
__global__ __launch_bounds__(1024)
void k_scan(const u64* __restrict__ M, const float4* __restrict__ bx,
            float* __restrict__ out) {
    __shared__ u64 diag[NWORD * 64];     // 48128 B
    __shared__ u64 supp[NWORD];
    __shared__ int s_newkept[64];
    __shared__ int s_nk, s_rank;
    const int tid = threadIdx.x;

    for (int i = tid; i < NWORD * 64; i += 1024) {
        int c = i >> 6, j = i & 63;
        int row = c * 64 + j;
        diag[i] = (row < PRE_TOPN) ? M[(size_t)row * NWORD + c] : 0ull;
    }
    if (tid < NWORD) supp[tid] = 0ull;
    if (tid == 0) s_rank = 0;
    __syncthreads();

    for (int c = 0; c < NWORD; ++c) {
        const int base = c * 64;
        if (tid < 64) {                      // wave 0: chase
            const int j = base + tid;
            const bool valid = j < PRE_TOPN;
            u64 m = diag[base + tid];
            u64 alive = __ballot(valid) & ~supp[c];
            u64 kept = 0ull;
            while (alive) {
                int k = (int)__builtin_ctzll(alive);
                kept |= (1ull << k);
                u32 mlo = (u32)__builtin_amdgcn_readlane((int)(u32)m, k);
                u32 mhi = (u32)__builtin_amdgcn_readlane((int)(u32)(m >> 32), k);
                u64 mk = ((u64)mhi << 32) | mlo;
                alive &= ~mk;
                alive &= ~(1ull << k);
            }
            int r0 = s_rank;                 // read before lane-0 update (in-order wave)
            if (valid && ((kept >> tid) & 1ull)) {
                int rin = (int)__popcll(kept & ((1ull << tid) - 1ull));
                s_newkept[rin] = j;
                int r = r0 + rin;
                if (r < POST_TOPN) {
                    float4 b = bx[j];
                    out[r * 5 + 0] = 0.f;
                    out[r * 5 + 1] = b.x; out[r * 5 + 2] = b.y;
                    out[r * 5 + 3] = b.z; out[r * 5 + 4] = b.w;
                }
            }
            if (tid == 0) { s_nk = (int)__popcll(kept); s_rank = r0 + (int)__popcll(kept); }
        }
        __syncthreads();
        if (s_rank >= POST_TOPN) break;      // uniform
        const int nk = s_nk;
        const int nw = NWORD - 1 - c;
        if (nk > 0 && nw > 0) {
            const int total = nw * nk;       // one load + one LDS atomicOr per pair
            for (int p = tid; p < total; p += 1024) {
                int w = c + 1 + p / nk;
                int k = p - nk * (p / nk);
                int j = s_newkept[k];
                u64 row = M[(size_t)j * NWORD + w];
                if (row) atomicOr(&supp[w], row);
            }
        }
        __syncthreads();
    }
}

// ---------------- launch ------------------------------------------------------
extern "C" void kernel_launch(void* const* d_in, const int* in_sizes, int n_in,
                              void* d_out, int out_size, void* d_ws, size_t ws_size,
                              hipStream_t stream) {
    const float* scores  = (const float*)d_in[0];   // (1,18,100,100)
    const float* bbox    = (const float*)d_in[1];   // (1,36,100,100)
    const float* im_info = (const float*)d_in[2];   // (3,)
    float* out = (float*)d_out;                     // 300*5 rows then 90000*4 anchors

    // workspace layout
    u64*    keys  = (u64*)d_ws;                                      // 65536 B
    float4* boxes = (float4*)((char*)d_ws + PADN * sizeof(u64));     // 96000 B
    u32*    meta  = (u32*)((char*)d_ws + 161536);                    // 8 B
    u32*    hist  = (u32*)((char*)d_ws + 163840);                    // 32768 B
    u64*    M     = (u64*)((char*)d_ws + 196608);                    // 4,512,000 B

    k_anchors_zero<<<(NANCH + 255) / 256, 256, 0, stream>>>(
        (float4*)(out + POST_TOPN * 5), hist, keys, out);
    k_hist_grid<<<45, 1024, 0, stream>>>(scores, hist);
    k_thresh<<<1, 1024, 0, stream>>>(hist, meta);
    k_compact<<<(NANCH + 255) / 256, 256, 0, stream>>>(scores, meta, keys);
    k_locsort<<<NLIST, 512, 0, stream>>>(keys);
    k_rank_decode<<<PADN / 256, 256, 0, stream>>>(keys, bbox, im_info, boxes);
    dim3 g(NWORD, NWORD);
    k_iou<<<g, 64, 0, stream>>>(boxes, M);
    k_scan<<<1, 1024, 0, stream>>>(M, boxes, out);
}